// Round 6
// baseline (165.810 us; speedup 1.0000x reference)
//
#include <hip/hip_runtime.h>
#include <hip/hip_cooperative_groups.h>
#include <math.h>

namespace cg = cooperative_groups;

#define EPS 1e-8f
#define NPATCH 196
#define HW 50176
#define LOG2E 1.4426950408889634f

// ws float offsets
#define GRAM_OFF 0        // 10
#define GQ_OFF 64         // 784*4
#define PART_OFF 4096     // 392
#define WA_OFF 16384      // bf16[768*768]  = 294912 float slots
#define XPB_OFF 311296    // bf16[784*768]  = 301056 float slots

typedef __attribute__((ext_vector_type(8))) short short8;
typedef __attribute__((ext_vector_type(4))) float f32x4;

static __device__ __forceinline__ unsigned short f2bf(float f) {
    unsigned u = __float_as_uint(f);
    u += 0x8000u + ((u >> 16) & 1u);     // RNE
    return (unsigned short)(u >> 16);
}

// ---- phase helpers (shared by cooperative and split paths) ----

// one 8-float chunk: idx in [0, 73728) -> WA, [73728, 148992) -> XPB
static __device__ __forceinline__ void do_convert(int idx,
                                                  const float* __restrict__ x,
                                                  const float* __restrict__ paw,
                                                  float* __restrict__ ws) {
    if (idx < 73728) {
        const float4* src = (const float4*)paw + (size_t)idx * 2;
        float4 a = src[0], b = src[1];
        short8 o;
        o[0] = f2bf(a.x); o[1] = f2bf(a.y); o[2] = f2bf(a.z); o[3] = f2bf(a.w);
        o[4] = f2bf(b.x); o[5] = f2bf(b.y); o[6] = f2bf(b.z); o[7] = f2bf(b.w);
        *(short8*)((unsigned short*)(ws + WA_OFF) + (size_t)idx * 8) = o;
    } else {
        int f8 = idx - 73728;                  // 0..75263
        int gp = f8 / 96;
        int e = (f8 - gp * 96) * 8;
        int b = gp / NPATCH, m = gp - b * NPATCH;
        int hp = m / 14, wq = m - hp * 14;
        int c = e >> 8, rem = e & 255, pr = rem >> 4, q0 = rem & 15;
        const float* src = x + ((size_t)(b * 3 + c) * 224 + hp * 16 + pr) * 224
                             + wq * 16 + q0;
        float4 a = *(const float4*)src;
        float4 b2 = *(const float4*)(src + 4);
        short8 o;
        o[0] = f2bf(a.x);  o[1] = f2bf(a.y);  o[2] = f2bf(a.z);  o[3] = f2bf(a.w);
        o[4] = f2bf(b2.x); o[5] = f2bf(b2.y); o[6] = f2bf(b2.z); o[7] = f2bf(b2.w);
        *(short8*)((unsigned short*)(ws + XPB_OFF) + (size_t)gp * 768 + e) = o;
    }
}

static __device__ __forceinline__ void do_gram(int t, float* shm,
                                               const float* __restrict__ pixw,
                                               const float* __restrict__ pixb,
                                               float* __restrict__ ws) {
    float g[10];
    #pragma unroll
    for (int j = 0; j < 10; ++j) g[j] = 0.f;
    for (int d = t; d < 768; d += 512) {
        float w0 = pixw[d*3+0], w1 = pixw[d*3+1], w2 = pixw[d*3+2], b = pixb[d];
        g[0] = fmaf(w0, w0, g[0]); g[1] = fmaf(w0, w1, g[1]);
        g[2] = fmaf(w0, w2, g[2]); g[3] = fmaf(w0, b,  g[3]);
        g[4] = fmaf(w1, w1, g[4]); g[5] = fmaf(w1, w2, g[5]);
        g[6] = fmaf(w1, b,  g[6]); g[7] = fmaf(w2, w2, g[7]);
        g[8] = fmaf(w2, b,  g[8]); g[9] = fmaf(b,  b,  g[9]);
    }
    #pragma unroll
    for (int off = 32; off; off >>= 1)
        #pragma unroll
        for (int j = 0; j < 10; ++j) g[j] += __shfl_down(g[j], off);
    int wv = t >> 6, ln = t & 63;
    if (ln == 0)
        for (int j = 0; j < 10; ++j) shm[wv * 10 + j] = g[j];
    __syncthreads();
    if (t < 10) {
        float s = 0.f;
        #pragma unroll
        for (int w = 0; w < 8; ++w) s += shm[w * 10 + t];
        ws[GRAM_OFF + t] = s;
    }
    __syncthreads();
}

// one 16-patch column tile: full 768-dim GEMM, 8 waves x 6 mtiles each.
static __device__ __forceinline__ void do_gemm_tile(int tile, int t, float* shm,
                                                    const float* __restrict__ pixw,
                                                    const float* __restrict__ pixb,
                                                    const float* __restrict__ pab,
                                                    float* __restrict__ ws) {
    const unsigned short* WA  = (const unsigned short*)(ws + WA_OFF);
    const unsigned short* XPB = (const unsigned short*)(ws + XPB_OFF);
    int lane = t & 63, wv = t >> 6;          // wv 0..7
    int ra = lane & 15, kg = lane >> 4;
    int n0 = tile * 16;
    const short8* pbv = (const short8*)(XPB + (size_t)(n0 + ra) * 768 + kg * 8);
    int mtb = wv * 6;                        // 6 mtiles per wave, 48 total
    const short8* pav = (const short8*)(WA + (size_t)(mtb * 16 + ra) * 768 + kg * 8);
    f32x4 acc[6];
    #pragma unroll
    for (int i = 0; i < 6; ++i) acc[i] = (f32x4){0.f, 0.f, 0.f, 0.f};
    #pragma unroll 4
    for (int kk = 0; kk < 24; ++kk) {
        short8 bfr = pbv[kk * 4];
        #pragma unroll
        for (int mt = 0; mt < 6; ++mt)
            acc[mt] = __builtin_amdgcn_mfma_f32_16x16x32_bf16(
                pav[(size_t)mt * 1536 + kk * 4], bfr, acc[mt], 0, 0, 0);
    }
    float sq = 0.f, dj0 = 0.f, dj1 = 0.f, dj2 = 0.f, dj3 = 0.f;
    #pragma unroll
    for (int mt = 0; mt < 6; ++mt)
        #pragma unroll
        for (int i = 0; i < 4; ++i) {
            int d = (mtb + mt) * 16 + kg * 4 + i;
            float v = acc[mt][i] + pab[d];
            sq  = fmaf(v, v, sq);
            dj0 = fmaf(pixw[d*3+0], v, dj0);
            dj1 = fmaf(pixw[d*3+1], v, dj1);
            dj2 = fmaf(pixw[d*3+2], v, dj2);
            dj3 = fmaf(pixb[d],     v, dj3);
        }
    sq  += __shfl_down(sq, 32);  dj0 += __shfl_down(dj0, 32);
    dj1 += __shfl_down(dj1, 32); dj2 += __shfl_down(dj2, 32);
    dj3 += __shfl_down(dj3, 32);
    sq  += __shfl_down(sq, 16);  dj0 += __shfl_down(dj0, 16);
    dj1 += __shfl_down(dj1, 16); dj2 += __shfl_down(dj2, 16);
    dj3 += __shfl_down(dj3, 16);
    if (lane < 16) {
        float* r = &shm[(wv * 16 + lane) * 5];
        r[0] = sq; r[1] = dj0; r[2] = dj1; r[3] = dj2; r[4] = dj3;
    }
    __syncthreads();
    if (t < 16) {
        float n2 = 0.f, e0 = 0.f, e1 = 0.f, e2 = 0.f, e3 = 0.f;
        #pragma unroll
        for (int w = 0; w < 8; ++w) {
            const float* r = &shm[(w * 16 + t) * 5];
            n2 += r[0]; e0 += r[1]; e1 += r[2]; e2 += r[3]; e3 += r[4];
        }
        float rq = 1.0f / fmaxf(sqrtf(n2), EPS);
        *(float4*)&ws[GQ_OFF + (n0 + t) * 4] =
            make_float4(e0 * rq, e1 * rq, e2 * rq, e3 * rq);
    }
    __syncthreads();
}

// one pixel unit u in [0,392): 512 pixels, deterministic partial -> PART[u]
static __device__ __forceinline__ void do_pixel_unit(int u, int t, float* shm,
                                                     const float* __restrict__ x,
                                                     float* __restrict__ ws) {
    int b = u / 98;
    int hw = (u - b * 98) * 512 + t;
    const float* xb = x + (size_t)b * (3 * HW);
    float c0 = xb[hw], c1 = xb[hw + HW], c2 = xb[hw + 2 * HW];

    float G0 = ws[0], G1 = ws[1], G2 = ws[2], G3 = ws[3], G4 = ws[4];
    float G5 = ws[5], G6 = ws[6], G7 = ws[7], G8 = ws[8], G9 = ws[9];
    float n2 = G9;
    n2 = fmaf(G0, c0 * c0, n2);
    n2 = fmaf(G4, c1 * c1, n2);
    n2 = fmaf(G7, c2 * c2, n2);
    float cross = fmaf(G1, c0 * c1, fmaf(G2, c0 * c2, fmaf(G5, c1 * c2,
                  fmaf(G3, c0, fmaf(G6, c1, G8 * c2)))));
    n2 = fmaf(2.0f, cross, n2);

    float rnp = 1.0f / fmaxf(sqrtf(n2), EPS);
    float es = 2.0f * rnp * LOG2E;
    float a0 = c0 * es, a1 = c1 * es, a2 = c2 * es;

    const float4* gq = (const float4*)(ws + GQ_OFF) + b * NPATCH;
    float sum = 0.0f;
    #pragma unroll 4
    for (int m = 0; m < NPATCH; ++m) {
        float4 g = gq[m];
        float tt = fmaf(a0, g.x, fmaf(a1, g.y, fmaf(a2, g.z, es * g.w)));
        sum += __builtin_amdgcn_exp2f(tt);
    }
    {
        int ne = hw % NPATCH;
        float4 g = gq[ne];
        float tt = fmaf(a0, g.x, fmaf(a1, g.y, fmaf(a2, g.z, es * g.w)));
        sum -= __builtin_amdgcn_exp2f(tt);
    }
    #pragma unroll
    for (int off = 32; off; off >>= 1) sum += __shfl_down(sum, off);
    __syncthreads();
    int wv = t >> 6, ln = t & 63;
    if (ln == 0) shm[wv] = sum;
    __syncthreads();
    if (t == 0) {
        float s = 0.f;
        #pragma unroll
        for (int w = 0; w < 8; ++w) s += shm[w];
        ws[PART_OFF + u] = s;
    }
}

static __device__ __forceinline__ void do_log(int t, float* shm,
                                              const float* __restrict__ ws,
                                              float* __restrict__ out) {
    float sum = (t < 392) ? ws[PART_OFF + t] : 0.f;
    #pragma unroll
    for (int off = 32; off; off >>= 1) sum += __shfl_down(sum, off);
    __syncthreads();
    int wv = t >> 6, ln = t & 63;
    if (ln == 0) shm[wv] = sum;
    __syncthreads();
    if (t == 0) {
        float s = 0.f;
        #pragma unroll
        for (int w = 0; w < 8; ++w) s += shm[w];
        out[0] = logf(s);
    }
}

// ---------------- cooperative all-in-one: 256 blocks x 512 ----------------
extern "C" __global__ void __launch_bounds__(512, 4)
k_all(const float* __restrict__ x, const float* __restrict__ pixw,
      const float* __restrict__ pixb, const float* __restrict__ paw,
      const float* __restrict__ pab, float* __restrict__ ws,
      float* __restrict__ out) {
    cg::grid_group grid = cg::this_grid();
    __shared__ float shm[640];
    int t = threadIdx.x;
    int bid = blockIdx.x;

    #pragma unroll
    for (int c = 0; c < 2; ++c) {
        int idx = c * 131072 + bid * 512 + t;
        if (idx < 148992) do_convert(idx, x, paw, ws);
    }
    if (bid == 255) do_gram(t, shm, pixw, pixb, ws);
    grid.sync();

    if (bid < 49) do_gemm_tile(bid, t, shm, pixw, pixb, pab, ws);
    grid.sync();

    for (int u = bid; u < 392; u += 256) do_pixel_unit(u, t, shm, x, ws);
    grid.sync();

    if (bid == 0) do_log(t, shm, ws, out);
}

// ---------------- split-path kernels (fallback if coop refused) ----------------
__global__ __launch_bounds__(512) void k_prep_s(const float* __restrict__ x,
                                                const float* __restrict__ pixw,
                                                const float* __restrict__ pixb,
                                                const float* __restrict__ paw,
                                                float* __restrict__ ws) {
    __shared__ float shm[80];
    int t = threadIdx.x, bid = blockIdx.x;
    if (bid < 291) {
        int idx = bid * 512 + t;
        if (idx < 148992) do_convert(idx, x, paw, ws);
    } else {
        do_gram(t, shm, pixw, pixb, ws);
    }
}

__global__ __launch_bounds__(512) void k_gemm_s(const float* __restrict__ pixw,
                                                const float* __restrict__ pixb,
                                                const float* __restrict__ pab,
                                                float* __restrict__ ws) {
    __shared__ float shm[640];
    do_gemm_tile(blockIdx.x, threadIdx.x, shm, pixw, pixb, pab, ws);
}

__global__ __launch_bounds__(512) void k_pixel_s(const float* __restrict__ x,
                                                 float* __restrict__ ws) {
    __shared__ float shm[8];
    do_pixel_unit(blockIdx.x, threadIdx.x, shm, x, ws);
}

__global__ __launch_bounds__(512) void k_log_s(const float* __restrict__ ws,
                                               float* __restrict__ out) {
    __shared__ float shm[8];
    do_log(threadIdx.x, shm, ws, out);
}

extern "C" void kernel_launch(void* const* d_in, const int* in_sizes, int n_in,
                              void* d_out, int out_size, void* d_ws, size_t ws_size,
                              hipStream_t stream) {
    (void)in_sizes; (void)n_in; (void)out_size; (void)ws_size;
    const float* x    = (const float*)d_in[0];
    const float* pixw = (const float*)d_in[1];
    const float* pixb = (const float*)d_in[2];
    const float* paw  = (const float*)d_in[3];
    const float* pab  = (const float*)d_in[4];
    float* ws  = (float*)d_ws;
    float* out = (float*)d_out;

    void* args[] = {(void*)&x, (void*)&pixw, (void*)&pixb, (void*)&paw,
                    (void*)&pab, (void*)&ws, (void*)&out};
    hipError_t e = hipLaunchCooperativeKernel((void*)k_all, dim3(256), dim3(512),
                                              args, 0, stream);
    if (e != hipSuccess) {
        // cooperative refused (or capture-unsupported): same phases, 4 launches
        hipLaunchKernelGGL(k_prep_s,  dim3(292), dim3(512), 0, stream, x, pixw, pixb, paw, ws);
        hipLaunchKernelGGL(k_gemm_s,  dim3(49),  dim3(512), 0, stream, pixw, pixb, pab, ws);
        hipLaunchKernelGGL(k_pixel_s, dim3(392), dim3(512), 0, stream, x, ws);
        hipLaunchKernelGGL(k_log_s,   dim3(1),   dim3(512), 0, stream, ws, out);
    }
}

// Round 7
// 56.001 us; speedup vs baseline: 2.9608x; 2.9608x over previous
//
#include <hip/hip_runtime.h>
#include <math.h>

#define EPS 1e-8f
#define NPATCH 196
#define HW 50176
#define LOG2E 1.4426950408889634f

// ws float offsets
#define P5_OFF 64          // 48*784       norm^2 partials   [mtile][gp]
#define DJ_OFF 40960       // 48*784*4     basis-dot partials[mtile][gp][4]
#define PART_OFF 196608    // 392          per-block pixel partials

typedef __attribute__((ext_vector_type(8))) short short8;
typedef __attribute__((ext_vector_type(4))) float f32x4;

static __device__ __forceinline__ unsigned short f2bf(float f) {
    unsigned u = __float_as_uint(f);
    u += 0x8000u + ((u >> 16) & 1u);     // RNE
    return (unsigned short)(u >> 16);
}

static __device__ __forceinline__ short8 cvt8(float4 a, float4 b) {
    short8 o;
    o[0] = f2bf(a.x); o[1] = f2bf(a.y); o[2] = f2bf(a.z); o[3] = f2bf(a.w);
    o[4] = f2bf(b.x); o[5] = f2bf(b.y); o[6] = f2bf(b.z); o[7] = f2bf(b.w);
    return o;
}

// 588 blocks x 256 (4 waves). wave -> one 16x16 mtile x ntile C-tile, K=768.
// Loads A (paw) and B (x gather) as f32, converts to bf16 in-register.
// Emits per-(mtile, patch): sq = sum v^2, dj[4] = sum basis_j * v.
__global__ __launch_bounds__(256) void k_gemm(const float* __restrict__ x,
                                              const float* __restrict__ pixw,
                                              const float* __restrict__ pixb,
                                              const float* __restrict__ paw,
                                              const float* __restrict__ pab,
                                              float* __restrict__ ws) {
    int t = threadIdx.x;
    int lane = t & 63, wv = t >> 6;
    int bid = blockIdx.x;
    int msup = bid / 49;
    int ntile = bid - msup * 49;
    int mtile = msup * 4 + wv;
    int m0 = mtile * 16, n0 = ntile * 16;
    int ra = lane & 15, kg = lane >> 4;

    const float* pa = paw + (size_t)(m0 + ra) * 768 + kg * 8;

    int gp = n0 + ra;
    int b = gp / NPATCH, m = gp - b * NPATCH;
    int hp = m / 14, wq = m - hp * 14;
    const float* xb0 = x + (size_t)b * (3 * HW) + (hp * 16) * 224 + wq * 16;

    f32x4 acc = {0.f, 0.f, 0.f, 0.f};
    #pragma unroll 4
    for (int kk = 0; kk < 24; ++kk) {
        int k = kg * 8 + kk * 32;
        float4 a0 = *(const float4*)(pa + kk * 32);
        float4 a1 = *(const float4*)(pa + kk * 32 + 4);
        int c = k >> 8, rem = k & 255, pr = rem >> 4, q0 = rem & 15;
        const float* bs = xb0 + c * HW + pr * 224 + q0;
        float4 b0 = *(const float4*)bs;
        float4 b1 = *(const float4*)(bs + 4);
        acc = __builtin_amdgcn_mfma_f32_16x16x32_bf16(cvt8(a0, a1), cvt8(b0, b1),
                                                      acc, 0, 0, 0);
    }

    // C[row][col]: col = lane&15 (patch), row = kg*4 + i (dim in tile)
    float sq = 0.f, d0 = 0.f, d1 = 0.f, d2 = 0.f, d3 = 0.f;
    #pragma unroll
    for (int i = 0; i < 4; ++i) {
        int d = m0 + kg * 4 + i;
        float v = acc[i] + pab[d];
        sq = fmaf(v, v, sq);
        d0 = fmaf(pixw[d*3+0], v, d0);
        d1 = fmaf(pixw[d*3+1], v, d1);
        d2 = fmaf(pixw[d*3+2], v, d2);
        d3 = fmaf(pixb[d],     v, d3);
    }
    sq += __shfl_down(sq, 32); d0 += __shfl_down(d0, 32);
    d1 += __shfl_down(d1, 32); d2 += __shfl_down(d2, 32);
    d3 += __shfl_down(d3, 32);
    sq += __shfl_down(sq, 16); d0 += __shfl_down(d0, 16);
    d1 += __shfl_down(d1, 16); d2 += __shfl_down(d2, 16);
    d3 += __shfl_down(d3, 16);
    if (lane < 16) {
        int g = n0 + lane;
        ws[P5_OFF + (size_t)mtile * 784 + g] = sq;
        *(float4*)&ws[DJ_OFF + ((size_t)mtile * 784 + g) * 4] =
            make_float4(d0, d1, d2, d3);
    }
}

// 392 blocks x 512: gram (in LDS) + GQ finalize for this image (in LDS) +
// 512-pixel exp-sum -> PART[bid]
__global__ __launch_bounds__(512) void k_pixel(const float* __restrict__ x,
                                               const float* __restrict__ pixw,
                                               const float* __restrict__ pixb,
                                               float* __restrict__ ws) {
    __shared__ float gtmp[8][10];
    __shared__ float gram_s[10];
    __shared__ float raw[NPATCH][5];
    __shared__ float gq[NPATCH][4];
    __shared__ float red[8];
    int t = threadIdx.x;
    int bid = blockIdx.x;
    int b = bid / 98;

    // ---- gram (10 floats), all blocks compute it (L2-hot broadcast) ----
    {
        float g[10];
        #pragma unroll
        for (int j = 0; j < 10; ++j) g[j] = 0.f;
        for (int d = t; d < 768; d += 512) {
            float w0 = pixw[d*3+0], w1 = pixw[d*3+1], w2 = pixw[d*3+2], bb = pixb[d];
            g[0] = fmaf(w0, w0, g[0]); g[1] = fmaf(w0, w1, g[1]);
            g[2] = fmaf(w0, w2, g[2]); g[3] = fmaf(w0, bb, g[3]);
            g[4] = fmaf(w1, w1, g[4]); g[5] = fmaf(w1, w2, g[5]);
            g[6] = fmaf(w1, bb, g[6]); g[7] = fmaf(w2, w2, g[7]);
            g[8] = fmaf(w2, bb, g[8]); g[9] = fmaf(bb, bb, g[9]);
        }
        #pragma unroll
        for (int off = 32; off; off >>= 1)
            #pragma unroll
            for (int j = 0; j < 10; ++j) g[j] += __shfl_down(g[j], off);
        int wvv = t >> 6, ln = t & 63;
        if (ln == 0)
            #pragma unroll
            for (int j = 0; j < 10; ++j) gtmp[wvv][j] = g[j];
    }

    // ---- GQ for this image's 196 patches (reduce 48 mtile partials) ----
    // tasks: 0..195 -> P5(patch=task); 196..979 -> DJ(idx=task-196: p=idx>>2, comp=idx&3)
    for (int task = t; task < 980; task += 512) {
        float s = 0.f;
        if (task < NPATCH) {
            int g = b * NPATCH + task;
            #pragma unroll 8
            for (int i = 0; i < 48; ++i) s += ws[P5_OFF + (size_t)i * 784 + g];
            raw[task][0] = s;
        } else {
            int idx = task - NPATCH;
            int p = idx >> 2, comp = idx & 3;
            int g = b * NPATCH + p;
            #pragma unroll 8
            for (int i = 0; i < 48; ++i)
                s += ws[DJ_OFF + ((size_t)i * 784 + g) * 4 + comp];
            raw[p][1 + comp] = s;
        }
    }
    __syncthreads();
    if (t < 10)
        gram_s[t] = gtmp[0][t] + gtmp[1][t] + gtmp[2][t] + gtmp[3][t] +
                    gtmp[4][t] + gtmp[5][t] + gtmp[6][t] + gtmp[7][t];
    if (t < NPATCH) {
        float rq = 1.0f / fmaxf(sqrtf(raw[t][0]), EPS);
        gq[t][0] = raw[t][1] * rq;
        gq[t][1] = raw[t][2] * rq;
        gq[t][2] = raw[t][3] * rq;
        gq[t][3] = raw[t][4] * rq;
    }
    __syncthreads();

    // ---- pixel exp-sum over 196 patches ----
    int hw = (bid - b * 98) * 512 + t;
    const float* xb = x + (size_t)b * (3 * HW);
    float c0 = xb[hw], c1 = xb[hw + HW], c2 = xb[hw + 2 * HW];

    float G0 = gram_s[0], G1 = gram_s[1], G2 = gram_s[2], G3 = gram_s[3];
    float G4 = gram_s[4], G5 = gram_s[5], G6 = gram_s[6], G7 = gram_s[7];
    float G8 = gram_s[8], G9 = gram_s[9];
    float n2 = G9;
    n2 = fmaf(G0, c0 * c0, n2);
    n2 = fmaf(G4, c1 * c1, n2);
    n2 = fmaf(G7, c2 * c2, n2);
    float cross = fmaf(G1, c0 * c1, fmaf(G2, c0 * c2, fmaf(G5, c1 * c2,
                  fmaf(G3, c0, fmaf(G6, c1, G8 * c2)))));
    n2 = fmaf(2.0f, cross, n2);

    float rnp = 1.0f / fmaxf(sqrtf(n2), EPS);
    float es = 2.0f * rnp * LOG2E;
    float a0 = c0 * es, a1 = c1 * es, a2 = c2 * es;

    float sum = 0.0f;
    #pragma unroll 4
    for (int m = 0; m < NPATCH; ++m) {
        float4 g = *(const float4*)gq[m];
        float tt = fmaf(a0, g.x, fmaf(a1, g.y, fmaf(a2, g.z, es * g.w)));
        sum += __builtin_amdgcn_exp2f(tt);
    }
    {
        int ne = hw % NPATCH;
        float4 g = *(const float4*)gq[ne];
        float tt = fmaf(a0, g.x, fmaf(a1, g.y, fmaf(a2, g.z, es * g.w)));
        sum -= __builtin_amdgcn_exp2f(tt);
    }
    #pragma unroll
    for (int off = 32; off; off >>= 1) sum += __shfl_down(sum, off);
    int wvv = t >> 6, ln = t & 63;
    if (ln == 0) red[wvv] = sum;
    __syncthreads();
    if (t == 0) {
        float s = 0.f;
        #pragma unroll
        for (int w = 0; w < 8; ++w) s += red[w];
        ws[PART_OFF + bid] = s;
    }
}

__global__ __launch_bounds__(512) void k_log(const float* __restrict__ ws,
                                             float* __restrict__ out) {
    __shared__ float red[8];
    int t = threadIdx.x;
    float sum = (t < 392) ? ws[PART_OFF + t] : 0.f;
    #pragma unroll
    for (int off = 32; off; off >>= 1) sum += __shfl_down(sum, off);
    int wv = t >> 6, ln = t & 63;
    if (ln == 0) red[wv] = sum;
    __syncthreads();
    if (t == 0) {
        float s = 0.f;
        #pragma unroll
        for (int w = 0; w < 8; ++w) s += red[w];
        out[0] = logf(s);
    }
}

extern "C" void kernel_launch(void* const* d_in, const int* in_sizes, int n_in,
                              void* d_out, int out_size, void* d_ws, size_t ws_size,
                              hipStream_t stream) {
    (void)in_sizes; (void)n_in; (void)out_size; (void)ws_size;
    const float* x    = (const float*)d_in[0];
    const float* pixw = (const float*)d_in[1];
    const float* pixb = (const float*)d_in[2];
    const float* paw  = (const float*)d_in[3];
    const float* pab  = (const float*)d_in[4];
    float* ws  = (float*)d_ws;
    float* out = (float*)d_out;

    hipLaunchKernelGGL(k_gemm,  dim3(588), dim3(256), 0, stream,
                       x, pixw, pixb, paw, pab, ws);
    hipLaunchKernelGGL(k_pixel, dim3(392), dim3(512), 0, stream,
                       x, pixw, pixb, ws);
    hipLaunchKernelGGL(k_log,   dim3(1),   dim3(512), 0, stream, ws, out);
}

// Round 8
// 54.096 us; speedup vs baseline: 3.0651x; 1.0352x over previous
//
#include <hip/hip_runtime.h>
#include <math.h>

#define EPS 1e-8f
#define NPATCH 196
#define HW 50176
#define LOG2E 1.4426950408889634f

// ws float offsets
#define P5T_OFF 64         // [gp][48]      norm^2 partials, patch-major
#define DJT_OFF 40960      // [gp][48][4]   basis-dot partials, patch-major
#define PART_OFF 196608    // 392           per-block pixel partials

typedef __attribute__((ext_vector_type(8))) short short8;
typedef __attribute__((ext_vector_type(4))) float f32x4;

static __device__ __forceinline__ unsigned short f2bf(float f) {
    unsigned u = __float_as_uint(f);
    u += 0x8000u + ((u >> 16) & 1u);     // RNE
    return (unsigned short)(u >> 16);
}

static __device__ __forceinline__ short8 cvt8(float4 a, float4 b) {
    short8 o;
    o[0] = f2bf(a.x); o[1] = f2bf(a.y); o[2] = f2bf(a.z); o[3] = f2bf(a.w);
    o[4] = f2bf(b.x); o[5] = f2bf(b.y); o[6] = f2bf(b.z); o[7] = f2bf(b.w);
    return o;
}

// 588 blocks x 256 (4 waves). wave -> one 16x16 mtile x ntile C-tile, K=768.
// Loads A (paw) and B (x gather) as f32, converts to bf16 in-register.
// Emits per-(patch, mtile): sq = sum v^2, dj[4] = sum basis_j * v  (patch-major).
__global__ __launch_bounds__(256) void k_gemm(const float* __restrict__ x,
                                              const float* __restrict__ pixw,
                                              const float* __restrict__ pixb,
                                              const float* __restrict__ paw,
                                              const float* __restrict__ pab,
                                              float* __restrict__ ws) {
    int t = threadIdx.x;
    int lane = t & 63, wv = t >> 6;
    int bid = blockIdx.x;
    int msup = bid / 49;
    int ntile = bid - msup * 49;
    int mtile = msup * 4 + wv;
    int m0 = mtile * 16, n0 = ntile * 16;
    int ra = lane & 15, kg = lane >> 4;

    const float* pa = paw + (size_t)(m0 + ra) * 768 + kg * 8;

    int gp = n0 + ra;
    int b = gp / NPATCH, m = gp - b * NPATCH;
    int hp = m / 14, wq = m - hp * 14;
    const float* xb0 = x + (size_t)b * (3 * HW) + (hp * 16) * 224 + wq * 16;

    f32x4 acc = {0.f, 0.f, 0.f, 0.f};
    #pragma unroll 4
    for (int kk = 0; kk < 24; ++kk) {
        int k = kg * 8 + kk * 32;
        float4 a0 = *(const float4*)(pa + kk * 32);
        float4 a1 = *(const float4*)(pa + kk * 32 + 4);
        int c = k >> 8, rem = k & 255, pr = rem >> 4, q0 = rem & 15;
        const float* bs = xb0 + c * HW + pr * 224 + q0;
        float4 b0 = *(const float4*)bs;
        float4 b1 = *(const float4*)(bs + 4);
        acc = __builtin_amdgcn_mfma_f32_16x16x32_bf16(cvt8(a0, a1), cvt8(b0, b1),
                                                      acc, 0, 0, 0);
    }

    // C[row][col]: col = lane&15 (patch), row = kg*4 + i (dim in tile)
    float sq = 0.f, d0 = 0.f, d1 = 0.f, d2 = 0.f, d3 = 0.f;
    #pragma unroll
    for (int i = 0; i < 4; ++i) {
        int d = m0 + kg * 4 + i;
        float v = acc[i] + pab[d];
        sq = fmaf(v, v, sq);
        d0 = fmaf(pixw[d*3+0], v, d0);
        d1 = fmaf(pixw[d*3+1], v, d1);
        d2 = fmaf(pixw[d*3+2], v, d2);
        d3 = fmaf(pixb[d],     v, d3);
    }
    sq += __shfl_down(sq, 32); d0 += __shfl_down(d0, 32);
    d1 += __shfl_down(d1, 32); d2 += __shfl_down(d2, 32);
    d3 += __shfl_down(d3, 32);
    sq += __shfl_down(sq, 16); d0 += __shfl_down(d0, 16);
    d1 += __shfl_down(d1, 16); d2 += __shfl_down(d2, 16);
    d3 += __shfl_down(d3, 16);
    if (lane < 16) {
        int g = n0 + lane;
        ws[P5T_OFF + (size_t)g * 48 + mtile] = sq;                    // patch-major
        *(float4*)&ws[DJT_OFF + ((size_t)g * 48 + mtile) * 4] =
            make_float4(d0, d1, d2, d3);
    }
}

// 392 blocks x 512: gram + GQ finalize (contiguous per-patch reduction, in LDS)
// + 512-pixel exp-sum -> PART[bid]
__global__ __launch_bounds__(512) void k_pixel(const float* __restrict__ x,
                                               const float* __restrict__ pixw,
                                               const float* __restrict__ pixb,
                                               float* __restrict__ ws) {
    __shared__ float gtmp[8][10];
    __shared__ float gram_s[10];
    __shared__ float raw[NPATCH][5];
    __shared__ float gq[NPATCH][4];
    __shared__ float red[8];
    int t = threadIdx.x;
    int bid = blockIdx.x;
    int b = bid / 98;

    // ---- gram (10 floats), per-block (L2-hot broadcast) ----
    {
        float g[10];
        #pragma unroll
        for (int j = 0; j < 10; ++j) g[j] = 0.f;
        for (int d = t; d < 768; d += 512) {
            float w0 = pixw[d*3+0], w1 = pixw[d*3+1], w2 = pixw[d*3+2], bb = pixb[d];
            g[0] = fmaf(w0, w0, g[0]); g[1] = fmaf(w0, w1, g[1]);
            g[2] = fmaf(w0, w2, g[2]); g[3] = fmaf(w0, bb, g[3]);
            g[4] = fmaf(w1, w1, g[4]); g[5] = fmaf(w1, w2, g[5]);
            g[6] = fmaf(w1, bb, g[6]); g[7] = fmaf(w2, w2, g[7]);
            g[8] = fmaf(w2, bb, g[8]); g[9] = fmaf(bb, bb, g[9]);
        }
        #pragma unroll
        for (int off = 32; off; off >>= 1)
            #pragma unroll
            for (int j = 0; j < 10; ++j) g[j] += __shfl_down(g[j], off);
        int wvv = t >> 6, ln = t & 63;
        if (ln == 0)
            #pragma unroll
            for (int j = 0; j < 10; ++j) gtmp[wvv][j] = g[j];
    }

    // ---- GQ for this image's 196 patches: contiguous patch-major reduction ----
    // thread t < 392: p = t>>1, h = t&1 -> mtiles [24h, 24h+24); pair-merge.
    if (t < 392) {
        int p = t >> 1, h = t & 1;
        int g = b * NPATCH + p;
        const float*  p5 = ws + P5T_OFF + (size_t)g * 48 + h * 24;
        const float4* dj = (const float4*)(ws + DJT_OFF) + (size_t)g * 48 + h * 24;
        float n2 = 0.f, e0 = 0.f, e1 = 0.f, e2 = 0.f, e3 = 0.f;
        #pragma unroll 8
        for (int i = 0; i < 24; ++i) {
            n2 += p5[i];
            float4 v = dj[i];
            e0 += v.x; e1 += v.y; e2 += v.z; e3 += v.w;
        }
        n2 += __shfl_down(n2, 1); e0 += __shfl_down(e0, 1);
        e1 += __shfl_down(e1, 1); e2 += __shfl_down(e2, 1);
        e3 += __shfl_down(e3, 1);
        if (h == 0) {
            raw[p][0] = n2; raw[p][1] = e0; raw[p][2] = e1;
            raw[p][3] = e2; raw[p][4] = e3;
        }
    }
    __syncthreads();
    if (t < 10)
        gram_s[t] = gtmp[0][t] + gtmp[1][t] + gtmp[2][t] + gtmp[3][t] +
                    gtmp[4][t] + gtmp[5][t] + gtmp[6][t] + gtmp[7][t];
    if (t < NPATCH) {
        float rq = 1.0f / fmaxf(sqrtf(raw[t][0]), EPS);
        gq[t][0] = raw[t][1] * rq;
        gq[t][1] = raw[t][2] * rq;
        gq[t][2] = raw[t][3] * rq;
        gq[t][3] = raw[t][4] * rq;
    }
    __syncthreads();

    // ---- pixel exp-sum over 196 patches ----
    int hw = (bid - b * 98) * 512 + t;
    const float* xb = x + (size_t)b * (3 * HW);
    float c0 = xb[hw], c1 = xb[hw + HW], c2 = xb[hw + 2 * HW];

    float G0 = gram_s[0], G1 = gram_s[1], G2 = gram_s[2], G3 = gram_s[3];
    float G4 = gram_s[4], G5 = gram_s[5], G6 = gram_s[6], G7 = gram_s[7];
    float G8 = gram_s[8], G9 = gram_s[9];
    float n2 = G9;
    n2 = fmaf(G0, c0 * c0, n2);
    n2 = fmaf(G4, c1 * c1, n2);
    n2 = fmaf(G7, c2 * c2, n2);
    float cross = fmaf(G1, c0 * c1, fmaf(G2, c0 * c2, fmaf(G5, c1 * c2,
                  fmaf(G3, c0, fmaf(G6, c1, G8 * c2)))));
    n2 = fmaf(2.0f, cross, n2);

    float rnp = 1.0f / fmaxf(sqrtf(n2), EPS);
    float es = 2.0f * rnp * LOG2E;
    float a0 = c0 * es, a1 = c1 * es, a2 = c2 * es;

    float sum = 0.0f;
    #pragma unroll 4
    for (int m = 0; m < NPATCH; ++m) {
        float4 g = *(const float4*)gq[m];
        float tt = fmaf(a0, g.x, fmaf(a1, g.y, fmaf(a2, g.z, es * g.w)));
        sum += __builtin_amdgcn_exp2f(tt);
    }
    {
        int ne = hw % NPATCH;
        float4 g = *(const float4*)gq[ne];
        float tt = fmaf(a0, g.x, fmaf(a1, g.y, fmaf(a2, g.z, es * g.w)));
        sum -= __builtin_amdgcn_exp2f(tt);
    }
    #pragma unroll
    for (int off = 32; off; off >>= 1) sum += __shfl_down(sum, off);
    int wvv = t >> 6, ln = t & 63;
    if (ln == 0) red[wvv] = sum;
    __syncthreads();
    if (t == 0) {
        float s = 0.f;
        #pragma unroll
        for (int w = 0; w < 8; ++w) s += red[w];
        ws[PART_OFF + bid] = s;
    }
}

__global__ __launch_bounds__(512) void k_log(const float* __restrict__ ws,
                                             float* __restrict__ out) {
    __shared__ float red[8];
    int t = threadIdx.x;
    float sum = (t < 392) ? ws[PART_OFF + t] : 0.f;
    #pragma unroll
    for (int off = 32; off; off >>= 1) sum += __shfl_down(sum, off);
    int wv = t >> 6, ln = t & 63;
    if (ln == 0) red[wv] = sum;
    __syncthreads();
    if (t == 0) {
        float s = 0.f;
        #pragma unroll
        for (int w = 0; w < 8; ++w) s += red[w];
        out[0] = logf(s);
    }
}

extern "C" void kernel_launch(void* const* d_in, const int* in_sizes, int n_in,
                              void* d_out, int out_size, void* d_ws, size_t ws_size,
                              hipStream_t stream) {
    (void)in_sizes; (void)n_in; (void)out_size; (void)ws_size;
    const float* x    = (const float*)d_in[0];
    const float* pixw = (const float*)d_in[1];
    const float* pixb = (const float*)d_in[2];
    const float* paw  = (const float*)d_in[3];
    const float* pab  = (const float*)d_in[4];
    float* ws  = (float*)d_ws;
    float* out = (float*)d_out;

    hipLaunchKernelGGL(k_gemm,  dim3(588), dim3(256), 0, stream,
                       x, pixw, pixb, paw, pab, ws);
    hipLaunchKernelGGL(k_pixel, dim3(392), dim3(512), 0, stream,
                       x, pixw, pixb, ws);
    hipLaunchKernelGGL(k_log,   dim3(1),   dim3(512), 0, stream, ws, out);
}

// Round 9
// 52.525 us; speedup vs baseline: 3.1568x; 1.0299x over previous
//
#include <hip/hip_runtime.h>
#include <math.h>

#define EPS 1e-8f
#define NPATCH 196
#define HW 50176
#define LOG2E 1.4426950408889634f

// ws float offsets
#define COUNT_OFF 0        // 1 int ticket counter
#define P5T_OFF 64         // [gp][48]      norm^2 partials, patch-major
#define DJT_OFF 40960      // [gp][48][4]   basis-dot partials, patch-major
#define PART_OFF 196608    // 392           per-block pixel partials
#define WA_OFF 212992      // bf16[768*768]  (147456 float slots)
#define XPB_OFF 360448     // bf16[784*768]  (150528 float slots)

typedef __attribute__((ext_vector_type(8))) short short8;
typedef __attribute__((ext_vector_type(4))) float f32x4;

static __device__ __forceinline__ unsigned short f2bf(float f) {
    unsigned u = __float_as_uint(f);
    u += 0x8000u + ((u >> 16) & 1u);     // RNE
    return (unsigned short)(u >> 16);
}

// ---- prep: pure streaming bf16 conversion ----
// blocks 0..287: WA = bf16(paw); blocks 288..581: XPB = bf16(gathered x)
__global__ __launch_bounds__(256) void k_prep(const float* __restrict__ x,
                                              const float* __restrict__ paw,
                                              float* __restrict__ ws) {
    int t = threadIdx.x;
    int bid = blockIdx.x;
    if (bid == 0 && t == 0) *(int*)(ws + COUNT_OFF) = 0;   // ticket reset
    if (bid < 288) {
        int f8 = bid * 256 + t;                    // 0..73727
        const float4* src = (const float4*)paw + (size_t)f8 * 2;
        float4 a = src[0], b = src[1];
        short8 o;
        o[0] = f2bf(a.x); o[1] = f2bf(a.y); o[2] = f2bf(a.z); o[3] = f2bf(a.w);
        o[4] = f2bf(b.x); o[5] = f2bf(b.y); o[6] = f2bf(b.z); o[7] = f2bf(b.w);
        *(short8*)((unsigned short*)(ws + WA_OFF) + (size_t)f8 * 8) = o;
    } else {
        int f8 = (bid - 288) * 256 + t;            // 0..75263
        int gp = f8 / 96;                          // 96 8-chunks per patch
        int e = (f8 - gp * 96) * 8;
        int b = gp / NPATCH, m = gp - b * NPATCH;
        int hp = m / 14, wq = m - hp * 14;
        int c = e >> 8, rem = e & 255, pr = rem >> 4, q0 = rem & 15;
        const float* src = x + ((size_t)(b * 3 + c) * 224 + hp * 16 + pr) * 224
                             + wq * 16 + q0;
        float4 a = *(const float4*)src;
        float4 b2 = *(const float4*)(src + 4);
        short8 o;
        o[0] = f2bf(a.x);  o[1] = f2bf(a.y);  o[2] = f2bf(a.z);  o[3] = f2bf(a.w);
        o[4] = f2bf(b2.x); o[5] = f2bf(b2.y); o[6] = f2bf(b2.z); o[7] = f2bf(b2.w);
        *(short8*)((unsigned short*)(ws + XPB_OFF) + (size_t)gp * 768 + e) = o;
    }
}

// 588 blocks x 256 (4 waves). wave -> one 16x16 C tile, K=768 in 24 MFMA.
// bf16 inputs from WA/XPB; emits patch-major per-(patch,mtile) partials.
__global__ __launch_bounds__(256) void k_gemm(const float* __restrict__ pixw,
                                              const float* __restrict__ pixb,
                                              const float* __restrict__ pab,
                                              float* __restrict__ ws) {
    const unsigned short* WA  = (const unsigned short*)(ws + WA_OFF);
    const unsigned short* XPB = (const unsigned short*)(ws + XPB_OFF);
    int t = threadIdx.x;
    int lane = t & 63, wv = t >> 6;
    int bid = blockIdx.x;
    int msup = bid / 49;
    int ntile = bid - msup * 49;
    int mtile = msup * 4 + wv;
    int m0 = mtile * 16, n0 = ntile * 16;
    int ra = lane & 15, kg = lane >> 4;
    const short8* pa = (const short8*)(WA  + (size_t)(m0 + ra) * 768 + kg * 8);
    const short8* pb = (const short8*)(XPB + (size_t)(n0 + ra) * 768 + kg * 8);
    f32x4 acc = {0.f, 0.f, 0.f, 0.f};
    #pragma unroll 6
    for (int kk = 0; kk < 24; ++kk) {
        short8 a = pa[kk * 4];
        short8 b = pb[kk * 4];
        acc = __builtin_amdgcn_mfma_f32_16x16x32_bf16(a, b, acc, 0, 0, 0);
    }
    // C[row][col]: col = lane&15 (patch), row = kg*4 + i (dim in tile)
    float sq = 0.f, d0 = 0.f, d1 = 0.f, d2 = 0.f, d3 = 0.f;
    #pragma unroll
    for (int i = 0; i < 4; ++i) {
        int d = m0 + kg * 4 + i;
        float v = acc[i] + pab[d];
        sq = fmaf(v, v, sq);
        d0 = fmaf(pixw[d*3+0], v, d0);
        d1 = fmaf(pixw[d*3+1], v, d1);
        d2 = fmaf(pixw[d*3+2], v, d2);
        d3 = fmaf(pixb[d],     v, d3);
    }
    sq += __shfl_down(sq, 32); d0 += __shfl_down(d0, 32);
    d1 += __shfl_down(d1, 32); d2 += __shfl_down(d2, 32);
    d3 += __shfl_down(d3, 32);
    sq += __shfl_down(sq, 16); d0 += __shfl_down(d0, 16);
    d1 += __shfl_down(d1, 16); d2 += __shfl_down(d2, 16);
    d3 += __shfl_down(d3, 16);
    if (lane < 16) {
        int g = n0 + lane;
        ws[P5T_OFF + (size_t)g * 48 + mtile] = sq;                 // patch-major
        *(float4*)&ws[DJT_OFF + ((size_t)g * 48 + mtile) * 4] =
            make_float4(d0, d1, d2, d3);
    }
}

// 392 blocks x 512: gram + GQ finalize (LDS) + 512-pixel exp-sum;
// last block (device ticket) reduces all 392 partials in fixed order + log.
__global__ __launch_bounds__(512) void k_pixel(const float* __restrict__ x,
                                               const float* __restrict__ pixw,
                                               const float* __restrict__ pixb,
                                               float* __restrict__ ws,
                                               float* __restrict__ out) {
    __shared__ float gtmp[8][10];
    __shared__ float gram_s[10];
    __shared__ float raw[NPATCH][5];
    __shared__ float gq[NPATCH][4];
    __shared__ float red[8];
    __shared__ int is_last;
    int t = threadIdx.x;
    int bid = blockIdx.x;
    int b = bid / 98;

    // ---- gram (10 floats), per-block (L2-hot broadcast) ----
    {
        float g[10];
        #pragma unroll
        for (int j = 0; j < 10; ++j) g[j] = 0.f;
        for (int d = t; d < 768; d += 512) {
            float w0 = pixw[d*3+0], w1 = pixw[d*3+1], w2 = pixw[d*3+2], bb = pixb[d];
            g[0] = fmaf(w0, w0, g[0]); g[1] = fmaf(w0, w1, g[1]);
            g[2] = fmaf(w0, w2, g[2]); g[3] = fmaf(w0, bb, g[3]);
            g[4] = fmaf(w1, w1, g[4]); g[5] = fmaf(w1, w2, g[5]);
            g[6] = fmaf(w1, bb, g[6]); g[7] = fmaf(w2, w2, g[7]);
            g[8] = fmaf(w2, bb, g[8]); g[9] = fmaf(bb, bb, g[9]);
        }
        #pragma unroll
        for (int off = 32; off; off >>= 1)
            #pragma unroll
            for (int j = 0; j < 10; ++j) g[j] += __shfl_down(g[j], off);
        int wvv = t >> 6, ln = t & 63;
        if (ln == 0)
            #pragma unroll
            for (int j = 0; j < 10; ++j) gtmp[wvv][j] = g[j];
    }

    // ---- GQ: contiguous patch-major reduction (p = t>>1, half = t&1) ----
    if (t < 392) {
        int p = t >> 1, h = t & 1;
        int g = b * NPATCH + p;
        const float*  p5 = ws + P5T_OFF + (size_t)g * 48 + h * 24;
        const float4* dj = (const float4*)(ws + DJT_OFF) + (size_t)g * 48 + h * 24;
        float n2 = 0.f, e0 = 0.f, e1 = 0.f, e2 = 0.f, e3 = 0.f;
        #pragma unroll 8
        for (int i = 0; i < 24; ++i) {
            n2 += p5[i];
            float4 v = dj[i];
            e0 += v.x; e1 += v.y; e2 += v.z; e3 += v.w;
        }
        n2 += __shfl_down(n2, 1); e0 += __shfl_down(e0, 1);
        e1 += __shfl_down(e1, 1); e2 += __shfl_down(e2, 1);
        e3 += __shfl_down(e3, 1);
        if (h == 0) {
            raw[p][0] = n2; raw[p][1] = e0; raw[p][2] = e1;
            raw[p][3] = e2; raw[p][4] = e3;
        }
    }
    __syncthreads();
    if (t < 10)
        gram_s[t] = gtmp[0][t] + gtmp[1][t] + gtmp[2][t] + gtmp[3][t] +
                    gtmp[4][t] + gtmp[5][t] + gtmp[6][t] + gtmp[7][t];
    if (t < NPATCH) {
        float rq = 1.0f / fmaxf(sqrtf(raw[t][0]), EPS);
        gq[t][0] = raw[t][1] * rq;
        gq[t][1] = raw[t][2] * rq;
        gq[t][2] = raw[t][3] * rq;
        gq[t][3] = raw[t][4] * rq;
    }
    __syncthreads();

    // ---- pixel exp-sum over 196 patches ----
    int hw = (bid - b * 98) * 512 + t;
    const float* xb = x + (size_t)b * (3 * HW);
    float c0 = xb[hw], c1 = xb[hw + HW], c2 = xb[hw + 2 * HW];

    float G0 = gram_s[0], G1 = gram_s[1], G2 = gram_s[2], G3 = gram_s[3];
    float G4 = gram_s[4], G5 = gram_s[5], G6 = gram_s[6], G7 = gram_s[7];
    float G8 = gram_s[8], G9 = gram_s[9];
    float n2 = G9;
    n2 = fmaf(G0, c0 * c0, n2);
    n2 = fmaf(G4, c1 * c1, n2);
    n2 = fmaf(G7, c2 * c2, n2);
    float cross = fmaf(G1, c0 * c1, fmaf(G2, c0 * c2, fmaf(G5, c1 * c2,
                  fmaf(G3, c0, fmaf(G6, c1, G8 * c2)))));
    n2 = fmaf(2.0f, cross, n2);

    float rnp = 1.0f / fmaxf(sqrtf(n2), EPS);
    float es = 2.0f * rnp * LOG2E;
    float a0 = c0 * es, a1 = c1 * es, a2 = c2 * es;

    float sum = 0.0f;
    #pragma unroll 4
    for (int m = 0; m < NPATCH; ++m) {
        float4 g = *(const float4*)gq[m];
        float tt = fmaf(a0, g.x, fmaf(a1, g.y, fmaf(a2, g.z, es * g.w)));
        sum += __builtin_amdgcn_exp2f(tt);
    }
    {
        int ne = hw % NPATCH;
        float4 g = *(const float4*)gq[ne];
        float tt = fmaf(a0, g.x, fmaf(a1, g.y, fmaf(a2, g.z, es * g.w)));
        sum -= __builtin_amdgcn_exp2f(tt);
    }
    #pragma unroll
    for (int off = 32; off; off >>= 1) sum += __shfl_down(sum, off);
    int wvv = t >> 6, ln = t & 63;
    if (ln == 0) red[wvv] = sum;
    __syncthreads();
    if (t == 0) {
        float s = 0.f;
        #pragma unroll
        for (int w = 0; w < 8; ++w) s += red[w];
        // device-scope release store of this block's partial
        __hip_atomic_store(&ws[PART_OFF + bid], s, __ATOMIC_RELEASE,
                           __HIP_MEMORY_SCOPE_AGENT);
        int old = __hip_atomic_fetch_add((int*)(ws + COUNT_OFF), 1,
                                         __ATOMIC_ACQ_REL,
                                         __HIP_MEMORY_SCOPE_AGENT);
        is_last = (old == 391);
    }
    __syncthreads();

    // ---- last block: deterministic fixed-order reduce + log ----
    if (is_last) {
        float v = 0.f;
        if (t < 392)
            v = __hip_atomic_load(&ws[PART_OFF + t], __ATOMIC_ACQUIRE,
                                  __HIP_MEMORY_SCOPE_AGENT);
        #pragma unroll
        for (int off = 32; off; off >>= 1) v += __shfl_down(v, off);
        __syncthreads();
        if ((t & 63) == 0) red[t >> 6] = v;
        __syncthreads();
        if (t == 0) {
            float s = 0.f;
            #pragma unroll
            for (int w = 0; w < 8; ++w) s += red[w];
            out[0] = logf(s);
        }
    }
}

extern "C" void kernel_launch(void* const* d_in, const int* in_sizes, int n_in,
                              void* d_out, int out_size, void* d_ws, size_t ws_size,
                              hipStream_t stream) {
    (void)in_sizes; (void)n_in; (void)out_size; (void)ws_size;
    const float* x    = (const float*)d_in[0];
    const float* pixw = (const float*)d_in[1];
    const float* pixb = (const float*)d_in[2];
    const float* paw  = (const float*)d_in[3];
    const float* pab  = (const float*)d_in[4];
    float* ws  = (float*)d_ws;
    float* out = (float*)d_out;

    hipLaunchKernelGGL(k_prep,  dim3(582), dim3(256), 0, stream, x, paw, ws);
    hipLaunchKernelGGL(k_gemm,  dim3(588), dim3(256), 0, stream,
                       pixw, pixb, pab, ws);
    hipLaunchKernelGGL(k_pixel, dim3(392), dim3(512), 0, stream,
                       x, pixw, pixb, ws, out);
}